// Round 6
// baseline (351.761 us; speedup 1.0000x reference)
//
#include <hip/hip_runtime.h>
#include <stdint.h>

typedef __attribute__((ext_vector_type(8))) short bf16x8;
typedef __attribute__((ext_vector_type(4))) float f32x4;

// ---------- helpers ----------
__device__ inline float u2f(unsigned v){ union{unsigned u; float f;} c; c.u=v; return c.f; }
__device__ inline unsigned short f2bf(float f){
  union{float f; unsigned u;} c; c.f=f;
  unsigned r = c.u + 0x7FFFu + ((c.u>>16)&1u);   // RNE
  return (unsigned short)(r>>16);
}
__device__ inline unsigned cvtpk_bf16(float lo, float hi){
  unsigned r;
  asm("v_cvt_pk_bf16_f32 %0, %1, %2" : "=v"(r) : "v"(lo), "v"(hi));
  return r;
}
__device__ inline void up8(uint4 u, float4& a0, float4& a1){
  a0.x = u2f(u.x<<16); a0.y = u2f(u.x & 0xFFFF0000u);
  a0.z = u2f(u.y<<16); a0.w = u2f(u.y & 0xFFFF0000u);
  a1.x = u2f(u.z<<16); a1.y = u2f(u.z & 0xFFFF0000u);
  a1.z = u2f(u.w<<16); a1.w = u2f(u.w & 0xFFFF0000u);
}

// device-scope spin barrier among NB csr blocks (all co-resident)
__device__ inline void gbar(int* ctr, int target){
  __syncthreads();
  __threadfence();                     // release: flush my dirty lines
  if (threadIdx.x == 0){
    atomicAdd(ctr, 1);
    while (atomicAdd(ctr, 0) < target) __builtin_amdgcn_s_sleep(8);
  }
  __syncthreads();
  __threadfence();                     // acquire: invalidate stale lines
}

// ---------- 1. prep: weights->bf16, bias concat, zero all counters ----------
__global__ void prep_w(const float* __restrict__ Wl, const float* __restrict__ Wr,
                       const float* __restrict__ bl, const float* __restrict__ br,
                       unsigned short* __restrict__ Wb, float* __restrict__ bcat,
                       int* __restrict__ counts, int* __restrict__ zeros4,
                       float* __restrict__ colsum, float* __restrict__ colsq, int n){
  int idx = blockIdx.x*blockDim.x + threadIdx.x;
  if (idx < 512*128){
    int j = idx >> 7, k = idx & 127;
    float v = (j < 256) ? Wl[j*128 + k] : Wr[(j-256)*128 + k];
    Wb[idx] = f2bf(v);
  }
  if (idx < 512) bcat[idx] = (idx < 256) ? bl[idx] : br[idx-256];
  if (idx < n) counts[idx] = 0;
  if (idx < 128){ colsum[idx] = 0.f; colsq[idx] = 0.f; }
  if (idx < 4) zeros4[idx] = 0;        // total, done, bar0, bar1
}

// ---------- 2. fused: MFMA GEMM (blocks < G) || full CSR build (blocks >= G) ----------
__launch_bounds__(256)
__global__ void gemm_csr(const float* __restrict__ x, const unsigned short* __restrict__ Wb,
                         const float* __restrict__ bcat,
                         unsigned short* __restrict__ xl, unsigned short* __restrict__ xr,
                         int n, int G,
                         const int* __restrict__ ei, int E,
                         int* __restrict__ counts, int* __restrict__ rank,
                         int* __restrict__ offs, int* __restrict__ ssrc,
                         int* __restrict__ total, int* __restrict__ bar0,
                         int* __restrict__ bar1){
  if ((int)blockIdx.x >= G){
    // ---- CSR side: 256 blocks ----
    const int NB = 256;
    int cb = blockIdx.x - G;
    // phase A: histogram + rank  (device-scope atomics -> coherent point)
    for (int e = cb*256 + threadIdx.x; e < E; e += NB*256)
      rank[e] = atomicAdd(&counts[ei[E + e]], 1);
    gbar(bar0, NB);
    // phase B: offset allocation (wave scan + one atomic per wave)
    {
      int i = cb*256 + threadIdx.x;     // NB*256 = 65536 >= n, single shot
      int lane = threadIdx.x & 63;
      int v = (i < n) ? counts[i] : 0;
      int incl = v;
      #pragma unroll
      for (int d = 1; d < 64; d <<= 1){
        int y = __shfl_up(incl, d);
        if (lane >= d) incl += y;
      }
      int wsum = __shfl(incl, 63);
      int base = 0;
      if (lane == 0) base = atomicAdd(total, wsum);
      base = __shfl(base, 0);
      if (i < n) offs[i] = base + incl - v;
    }
    gbar(bar1, NB);
    // phase C: scatter (atomic-free)
    for (int e = cb*256 + threadIdx.x; e < E; e += NB*256){
      int d = ei[E + e];
      ssrc[offs[d] + rank[e]] = ei[e];
    }
    return;
  }
  // ---- GEMM side: A=W (512 ch), B=x^T; 32 rows/wave ----
  int wave = threadIdx.x >> 6, lane = threadIdx.x & 63;
  int lr = lane & 15, kb = (lane >> 4) * 8;
  int rowbase = blockIdx.x*128 + wave*32;

  union FR { bf16x8 v; unsigned u[4]; uint4 u4; };
  FR bfr[2][4];
  int myrow[2]; bool wr[2];
  #pragma unroll
  for (int rg = 0; rg < 2; ++rg){
    myrow[rg] = rowbase + rg*16 + lr;
    int rc = myrow[rg] < n ? myrow[rg] : n-1;
    wr[rg] = myrow[rg] < n;
    const float* xp = &x[(size_t)rc*128];
    #pragma unroll
    for (int ks = 0; ks < 4; ++ks){
      float4 f0 = *reinterpret_cast<const float4*>(xp + ks*32 + kb);
      float4 f1 = *reinterpret_cast<const float4*>(xp + ks*32 + kb + 4);
      bfr[rg][ks].u[0] = cvtpk_bf16(f0.x, f0.y);
      bfr[rg][ks].u[1] = cvtpk_bf16(f0.z, f0.w);
      bfr[rg][ks].u[2] = cvtpk_bf16(f1.x, f1.y);
      bfr[rg][ks].u[3] = cvtpk_bf16(f1.z, f1.w);
    }
  }

  #pragma unroll 1
  for (int mt = 0; mt < 32; ++mt){
    FR afr[4];
    const unsigned short* wp = &Wb[(size_t)(mt*16 + lr)*128 + kb];
    #pragma unroll
    for (int ks = 0; ks < 4; ++ks)
      afr[ks].u4 = *reinterpret_cast<const uint4*>(wp + ks*32);
    f32x4 acc0 = (f32x4){0.f,0.f,0.f,0.f};
    f32x4 acc1 = (f32x4){0.f,0.f,0.f,0.f};
    #pragma unroll
    for (int ks = 0; ks < 4; ++ks){
      acc0 = __builtin_amdgcn_mfma_f32_16x16x32_bf16(afr[ks].v, bfr[0][ks].v, acc0, 0,0,0);
      acc1 = __builtin_amdgcn_mfma_f32_16x16x32_bf16(afr[ks].v, bfr[1][ks].v, acc1, 0,0,0);
    }
    int ch0 = mt*16 + (lane>>4)*4;
    float4 bi = *reinterpret_cast<const float4*>(&bcat[ch0]);
    unsigned short* dst = (ch0 < 256) ? xl : xr;
    int cc = ch0 & 255;
    if (wr[0]){
      uint2 o; o.x = cvtpk_bf16(acc0[0]+bi.x, acc0[1]+bi.y);
      o.y = cvtpk_bf16(acc0[2]+bi.z, acc0[3]+bi.w);
      *reinterpret_cast<uint2*>(&dst[(size_t)myrow[0]*256 + cc]) = o;
    }
    if (wr[1]){
      uint2 o; o.x = cvtpk_bf16(acc1[0]+bi.x, acc1[1]+bi.y);
      o.y = cvtpk_bf16(acc1[2]+bi.z, acc1[3]+bi.w);
      *reinterpret_cast<uint2*>(&dst[(size_t)myrow[1]*256 + cc]) = o;
    }
  }
}

// ---------- 3. node attention: uint4 gathers, depth-1 pipeline (r4 version) ----------
__device__ inline float dot8(const float4& a0, const float4& a1,
                             const float4& xr0, const float4& xr1,
                             const float4& at0, const float4& at1){
  float t, d;
  t = a0.x+xr0.x; t = fmaxf(t, 0.2f*t); d  = at0.x*t;
  t = a0.y+xr0.y; t = fmaxf(t, 0.2f*t); d += at0.y*t;
  t = a0.z+xr0.z; t = fmaxf(t, 0.2f*t); d += at0.z*t;
  t = a0.w+xr0.w; t = fmaxf(t, 0.2f*t); d += at0.w*t;
  t = a1.x+xr1.x; t = fmaxf(t, 0.2f*t); d += at1.x*t;
  t = a1.y+xr1.y; t = fmaxf(t, 0.2f*t); d += at1.y*t;
  t = a1.z+xr1.z; t = fmaxf(t, 0.2f*t); d += at1.z*t;
  t = a1.w+xr1.w; t = fmaxf(t, 0.2f*t); d += at1.w*t;
  return d;
}
__device__ inline float red16(float d){
  d += __shfl_xor(d, 1); d += __shfl_xor(d, 2);
  d += __shfl_xor(d, 4); d += __shfl_xor(d, 8);
  return d;
}

__launch_bounds__(128)
__global__ void node_attn(const unsigned short* __restrict__ xl,
                          const unsigned short* __restrict__ xr,
                          const float* __restrict__ att, const float* __restrict__ bias,
                          const int* __restrict__ offs, const int* __restrict__ counts,
                          const int* __restrict__ ssrc,
                          float* __restrict__ out, int n){
  int lane = threadIdx.x & 63;
  int v = blockIdx.x*2 + (threadIdx.x >> 6);
  if (v >= n) return;
  int half = lane >> 5, q5 = lane & 31, h = q5 >> 4, cq = q5 & 15;
  int fbase = h*128 + cq*8;

  float4 xr0, xr1;
  up8(*reinterpret_cast<const uint4*>(&xr[(size_t)v*256 + fbase]), xr0, xr1);
  float4 at0 = *reinterpret_cast<const float4*>(&att[fbase]);
  float4 at1 = *reinterpret_cast<const float4*>(&att[fbase + 4]);

  float4 sv0, sv1;
  up8(*reinterpret_cast<const uint4*>(&xl[(size_t)v*256 + fbase]), sv0, sv1);
  float dself = red16(dot8(sv0, sv1, xr0, xr1, at0, at1));
  float m, s; float4 ac0, ac1;
  if (half == 0){ m = dself; s = 1.f; ac0 = sv0; ac1 = sv1; }
  else { m = -1e30f; s = 0.f; ac0 = make_float4(0,0,0,0); ac1 = ac0; }

  int e0 = offs[v], cnt = counts[v];
  int halfoff = half*4;
  int e = 0;
  while (e < cnt){
    int take = cnt - e; if (take > 64) take = 64;
    int last = e0 + cnt - 1;
    int idx = e0 + e + lane; if (idx > last) idx = last;
    int batch = ssrc[idx];

    uint4 c0, c1, c2, c3;
    {
      int b = halfoff;
      int i0 = __shfl(batch, b),   i1 = __shfl(batch, b+1);
      int i2 = __shfl(batch, b+2), i3 = __shfl(batch, b+3);
      c0 = *reinterpret_cast<const uint4*>(&xl[(size_t)i0*256 + fbase]);
      c1 = *reinterpret_cast<const uint4*>(&xl[(size_t)i1*256 + fbase]);
      c2 = *reinterpret_cast<const uint4*>(&xl[(size_t)i2*256 + fbase]);
      c3 = *reinterpret_cast<const uint4*>(&xl[(size_t)i3*256 + fbase]);
    }
    for (int j = 0; j < take; j += 8){
      uint4 n0, n1, n2, n3;
      bool more = (j + 8) < take;
      if (more){
        int b = j + 8 + halfoff;
        int i0 = __shfl(batch, b),   i1 = __shfl(batch, b+1);
        int i2 = __shfl(batch, b+2), i3 = __shfl(batch, b+3);
        n0 = *reinterpret_cast<const uint4*>(&xl[(size_t)i0*256 + fbase]);
        n1 = *reinterpret_cast<const uint4*>(&xl[(size_t)i1*256 + fbase]);
        n2 = *reinterpret_cast<const uint4*>(&xl[(size_t)i2*256 + fbase]);
        n3 = *reinterpret_cast<const uint4*>(&xl[(size_t)i3*256 + fbase]);
      }
      float4 a00,a01,a10,a11,a20,a21,a30,a31;
      up8(c0, a00, a01); up8(c1, a10, a11);
      up8(c2, a20, a21); up8(c3, a30, a31);
      float d0 = red16(dot8(a00,a01,xr0,xr1,at0,at1));
      float d1 = red16(dot8(a10,a11,xr0,xr1,at0,at1));
      float d2 = red16(dot8(a20,a21,xr0,xr1,at0,at1));
      float d3 = red16(dot8(a30,a31,xr0,xr1,at0,at1));

      float p0e, p1e, p2e, p3e, f;
      if (j + 8 <= take){
        float nm = fmaxf(m, fmaxf(fmaxf(d0,d1), fmaxf(d2,d3)));
        f = __expf(m - nm);
        p0e = __expf(d0-nm); p1e = __expf(d1-nm);
        p2e = __expf(d2-nm); p3e = __expf(d3-nm);
        m = nm;
      } else {
        int b0 = j + halfoff;
        bool v0 = b0 < take, v1 = b0+1 < take, v2 = b0+2 < take, v3 = b0+3 < take;
        float dm0 = v0 ? d0 : -1e30f, dm1 = v1 ? d1 : -1e30f;
        float dm2 = v2 ? d2 : -1e30f, dm3 = v3 ? d3 : -1e30f;
        float nm = fmaxf(m, fmaxf(fmaxf(dm0,dm1), fmaxf(dm2,dm3)));
        f = __expf(m - nm);
        p0e = v0 ? __expf(d0-nm) : 0.f;
        p1e = v1 ? __expf(d1-nm) : 0.f;
        p2e = v2 ? __expf(d2-nm) : 0.f;
        p3e = v3 ? __expf(d3-nm) : 0.f;
        m = nm;
      }
      s = s*f + ((p0e+p1e)+(p2e+p3e));
      ac0.x = ac0.x*f + p0e*a00.x + p1e*a10.x + p2e*a20.x + p3e*a30.x;
      ac0.y = ac0.y*f + p0e*a00.y + p1e*a10.y + p2e*a20.y + p3e*a30.y;
      ac0.z = ac0.z*f + p0e*a00.z + p1e*a10.z + p2e*a20.z + p3e*a30.z;
      ac0.w = ac0.w*f + p0e*a00.w + p1e*a10.w + p2e*a20.w + p3e*a30.w;
      ac1.x = ac1.x*f + p0e*a01.x + p1e*a11.x + p2e*a21.x + p3e*a31.x;
      ac1.y = ac1.y*f + p0e*a01.y + p1e*a11.y + p2e*a21.y + p3e*a31.y;
      ac1.z = ac1.z*f + p0e*a01.z + p1e*a11.z + p2e*a21.z + p3e*a31.z;
      ac1.w = ac1.w*f + p0e*a01.w + p1e*a11.w + p2e*a21.w + p3e*a31.w;
      if (more){ c0 = n0; c1 = n1; c2 = n2; c3 = n3; }
    }
    e += take;
  }

  // merge half-wave streams (flash-combine across xor 32)
  float mo = __shfl_xor(m, 32), so = __shfl_xor(s, 32);
  float4 bo0, bo1;
  bo0.x = __shfl_xor(ac0.x, 32); bo0.y = __shfl_xor(ac0.y, 32);
  bo0.z = __shfl_xor(ac0.z, 32); bo0.w = __shfl_xor(ac0.w, 32);
  bo1.x = __shfl_xor(ac1.x, 32); bo1.y = __shfl_xor(ac1.y, 32);
  bo1.z = __shfl_xor(ac1.z, 32); bo1.w = __shfl_xor(ac1.w, 32);
  float mm = fmaxf(m, mo);
  float fa = __expf(m - mm), fb = __expf(mo - mm);
  s = s*fa + so*fb;
  ac0.x = ac0.x*fa + bo0.x*fb; ac0.y = ac0.y*fa + bo0.y*fb;
  ac0.z = ac0.z*fa + bo0.z*fb; ac0.w = ac0.w*fa + bo0.w*fb;
  ac1.x = ac1.x*fa + bo1.x*fb; ac1.y = ac1.y*fa + bo1.y*fb;
  ac1.z = ac1.z*fa + bo1.z*fb; ac1.w = ac1.w*fa + bo1.w*fb;
  float inv = 1.f/s;
  float w0x = ac0.x*inv, w0y = ac0.y*inv, w0z = ac0.z*inv, w0w = ac0.w*inv;
  float w1x = ac1.x*inv, w1y = ac1.y*inv, w1z = ac1.z*inv, w1w = ac1.w*inv;
  float o0x = __shfl_xor(w0x, 16), o0y = __shfl_xor(w0y, 16);
  float o0z = __shfl_xor(w0z, 16), o0w = __shfl_xor(w0w, 16);
  float o1x = __shfl_xor(w1x, 16), o1y = __shfl_xor(w1y, 16);
  float o1z = __shfl_xor(w1z, 16), o1w = __shfl_xor(w1w, 16);
  if (half == 0 && h == 0){
    float4 b0 = *reinterpret_cast<const float4*>(&bias[cq*8]);
    float4 b1 = *reinterpret_cast<const float4*>(&bias[cq*8 + 4]);
    float4 r0, r1;
    r0.x = 0.5f*(w0x+o0x) + b0.x; r0.y = 0.5f*(w0y+o0y) + b0.y;
    r0.z = 0.5f*(w0z+o0z) + b0.z; r0.w = 0.5f*(w0w+o0w) + b0.w;
    r1.x = 0.5f*(w1x+o1x) + b1.x; r1.y = 0.5f*(w1y+o1y) + b1.y;
    r1.z = 0.5f*(w1z+o1z) + b1.z; r1.w = 0.5f*(w1w+o1w) + b1.w;
    *reinterpret_cast<float4*>(&out[(size_t)v*128 + cq*8])     = r0;
    *reinterpret_cast<float4*>(&out[(size_t)v*128 + cq*8 + 4]) = r1;
  }
}

// ---------- 4. column sums + last-block stats ----------
__global__ void col_reduce(const float* __restrict__ out, int n,
                           float* __restrict__ colsum, float* __restrict__ colsq,
                           const float* __restrict__ ms, float* __restrict__ stats,
                           int* __restrict__ done){
  __shared__ float s1[256*4], s2[256*4];
  __shared__ int isLast;
  int t = threadIdx.x;
  int c4 = t & 31, rg = t >> 5;
  float4 sum = make_float4(0,0,0,0), sq = make_float4(0,0,0,0);
  for (int r = blockIdx.x*8 + rg; r < n; r += gridDim.x*8){
    float4 v = reinterpret_cast<const float4*>(out)[(size_t)r*32 + c4];
    sum.x += v.x; sum.y += v.y; sum.z += v.z; sum.w += v.w;
    sq.x += v.x*v.x; sq.y += v.y*v.y; sq.z += v.z*v.z; sq.w += v.w*v.w;
  }
  reinterpret_cast<float4*>(s1)[t] = sum;
  reinterpret_cast<float4*>(s2)[t] = sq;
  __syncthreads();
  if (t < 32){
    #pragma unroll
    for (int g = 1; g < 8; ++g){
      float4 a = reinterpret_cast<float4*>(s1)[t + g*32];
      float4 b = reinterpret_cast<float4*>(s2)[t + g*32];
      sum.x += a.x; sum.y += a.y; sum.z += a.z; sum.w += a.w;
      sq.x  += b.x; sq.y  += b.y; sq.z  += b.z; sq.w  += b.w;
    }
    atomicAdd(&colsum[t*4+0], sum.x); atomicAdd(&colsum[t*4+1], sum.y);
    atomicAdd(&colsum[t*4+2], sum.z); atomicAdd(&colsum[t*4+3], sum.w);
    atomicAdd(&colsq[t*4+0], sq.x);  atomicAdd(&colsq[t*4+1], sq.y);
    atomicAdd(&colsq[t*4+2], sq.z);  atomicAdd(&colsq[t*4+3], sq.w);
  }
  __syncthreads();
  if (t == 0){
    __threadfence();
    isLast = (atomicAdd(done, 1) == (int)gridDim.x - 1);
  }
  __syncthreads();
  if (isLast && t < 128){
    float invn = 1.f/(float)n;
    float mu  = colsum[t]*invn;
    float ex2 = colsq[t]*invn;
    float mm  = ms[t];
    float var = ex2 - 2.f*mm*mu*mu + mm*mm*mu*mu;
    stats[t]     = mm*mu;
    stats[128+t] = rsqrtf(var + 1e-5f);
  }
}

// ---------- 5. normalize + ELU + residual ----------
__global__ void final_ew(float* __restrict__ out, const float* __restrict__ x,
                         const float* __restrict__ stats, const float* __restrict__ gw,
                         const float* __restrict__ gb, int n){
  int total = n*32;
  for (int i = blockIdx.x*blockDim.x + threadIdx.x; i < total; i += gridDim.x*blockDim.x){
    int c4 = i & 31;
    float4 o  = reinterpret_cast<float4*>(out)[i];
    float4 xv = reinterpret_cast<const float4*>(x)[i];
    float4 sh = reinterpret_cast<const float4*>(stats)[c4];
    float4 rs = reinterpret_cast<const float4*>(stats)[32 + c4];
    float4 w4 = reinterpret_cast<const float4*>(gw)[c4];
    float4 b4 = reinterpret_cast<const float4*>(gb)[c4];
    float y0 = w4.x*((o.x - sh.x)*rs.x) + b4.x;  y0 = y0 > 0.f ? y0 : expm1f(y0);
    float y1 = w4.y*((o.y - sh.y)*rs.y) + b4.y;  y1 = y1 > 0.f ? y1 : expm1f(y1);
    float y2 = w4.z*((o.z - sh.z)*rs.z) + b4.z;  y2 = y2 > 0.f ? y2 : expm1f(y2);
    float y3 = w4.w*((o.w - sh.w)*rs.w) + b4.w;  y3 = y3 > 0.f ? y3 : expm1f(y3);
    o.x = y0 + xv.x; o.y = y1 + xv.y; o.z = y2 + xv.z; o.w = y3 + xv.w;
    reinterpret_cast<float4*>(out)[i] = o;
  }
}

// ---------- launch ----------
extern "C" void kernel_launch(void* const* d_in, const int* in_sizes, int n_in,
                              void* d_out, int out_size, void* d_ws, size_t ws_size,
                              hipStream_t stream){
  const float* x    = (const float*)d_in[0];
  const int*   ei   = (const int*)  d_in[1];
  const float* Wl   = (const float*)d_in[2];
  const float* bl   = (const float*)d_in[3];
  const float* Wr   = (const float*)d_in[4];
  const float* br   = (const float*)d_in[5];
  const float* att  = (const float*)d_in[6];
  const float* bias = (const float*)d_in[7];
  const float* gw   = (const float*)d_in[8];
  const float* gb   = (const float*)d_in[9];
  const float* gms  = (const float*)d_in[10];
  int n = in_sizes[0] / 128;
  int E = in_sizes[1] / 2;
  float* outp = (float*)d_out;

  char* w = (char*)d_ws;
  size_t off = 0;
  auto alloc = [&](size_t bytes)->char*{
    char* p = w + off; off += (bytes + 255) & ~(size_t)255; return p;
  };
  unsigned short* xl  = (unsigned short*)alloc((size_t)n*256*2);
  unsigned short* xr  = (unsigned short*)alloc((size_t)n*256*2);
  unsigned short* Wb  = (unsigned short*)alloc(512*128*2);
  float* bcat   = (float*)alloc(512*4);
  int*   counts = (int*)  alloc((size_t)n*4);
  int*   offs   = (int*)  alloc((size_t)n*4);
  int*   zeros4 = (int*)  alloc(4*4);   // total, done, bar0, bar1
  int*   rank   = (int*)  alloc((size_t)E*4);
  int*   ssrc   = (int*)  alloc((size_t)E*4);
  float* colsum = (float*)alloc(128*4);
  float* colsq  = (float*)alloc(128*4);
  float* stats  = (float*)alloc(256*4);
  if (off > ws_size) return;
  int* total = zeros4 + 0;
  int* done  = zeros4 + 1;
  int* bar0  = zeros4 + 2;
  int* bar1  = zeros4 + 3;

  int G = (n + 127) / 128;
  prep_w    <<<256, 256, 0, stream>>>(Wl, Wr, bl, br, Wb, bcat, counts, zeros4, colsum, colsq, n);
  gemm_csr  <<<G + 256, 256, 0, stream>>>(x, Wb, bcat, xl, xr, n, G, ei, E,
                                          counts, rank, offs, ssrc, total, bar0, bar1);
  node_attn <<<(n+1)/2, 128, 0, stream>>>(xl, xr, att, bias, offs, counts, ssrc, outp, n);
  col_reduce<<<512, 256, 0, stream>>>(outp, n, colsum, colsq, gms, stats, done);
  final_ew  <<<2048, 256, 0, stream>>>(outp, x, stats, gw, gb, n);
}

// Round 7
// 249.224 us; speedup vs baseline: 1.4114x; 1.4114x over previous
//
#include <hip/hip_runtime.h>
#include <stdint.h>

typedef __attribute__((ext_vector_type(8))) short bf16x8;
typedef __attribute__((ext_vector_type(4))) float f32x4;

// ---------- helpers ----------
__device__ inline float u2f(unsigned v){ union{unsigned u; float f;} c; c.u=v; return c.f; }
__device__ inline unsigned short f2bf(float f){
  union{float f; unsigned u;} c; c.f=f;
  unsigned r = c.u + 0x7FFFu + ((c.u>>16)&1u);   // RNE
  return (unsigned short)(r>>16);
}
__device__ inline unsigned cvtpk_bf16(float lo, float hi){
  unsigned r;
  asm("v_cvt_pk_bf16_f32 %0, %1, %2" : "=v"(r) : "v"(lo), "v"(hi));
  return r;
}
__device__ inline void up8(uint4 u, float4& a0, float4& a1){
  a0.x = u2f(u.x<<16); a0.y = u2f(u.x & 0xFFFF0000u);
  a0.z = u2f(u.y<<16); a0.w = u2f(u.y & 0xFFFF0000u);
  a1.x = u2f(u.z<<16); a1.y = u2f(u.z & 0xFFFF0000u);
  a1.z = u2f(u.w<<16); a1.w = u2f(u.w & 0xFFFF0000u);
}

// ---------- 1. prep: weights->bf16, bias concat, zero all counters ----------
__global__ void prep_w(const float* __restrict__ Wl, const float* __restrict__ Wr,
                       const float* __restrict__ bl, const float* __restrict__ br,
                       unsigned short* __restrict__ Wb, float* __restrict__ bcat,
                       int* __restrict__ counts, int* __restrict__ zeros4,
                       float* __restrict__ colsum, float* __restrict__ colsq, int n){
  int idx = blockIdx.x*blockDim.x + threadIdx.x;
  if (idx < 512*128){
    int j = idx >> 7, k = idx & 127;
    float v = (j < 256) ? Wl[j*128 + k] : Wr[(j-256)*128 + k];
    Wb[idx] = f2bf(v);
  }
  if (idx < 512) bcat[idx] = (idx < 256) ? bl[idx] : br[idx-256];
  if (idx < n) counts[idx] = 0;
  if (idx < 128){ colsum[idx] = 0.f; colsq[idx] = 0.f; }
  if (idx < 4) zeros4[idx] = 0;        // total, done
}

// ---------- 2. fused: bf16 MFMA GEMM (blocks < G) || dst histogram (blocks >= G) ----------
__launch_bounds__(256)
__global__ void gemm_hist(const float* __restrict__ x, const unsigned short* __restrict__ Wb,
                          const float* __restrict__ bcat,
                          unsigned short* __restrict__ xl, unsigned short* __restrict__ xr,
                          int n, int G,
                          const int* __restrict__ ei, int E,
                          int* __restrict__ counts, int* __restrict__ rank){
  if ((int)blockIdx.x >= G){
    int hb = blockIdx.x - G;
    int nb = gridDim.x - G;
    for (int e = hb*256 + threadIdx.x; e < E; e += nb*256)
      rank[e] = atomicAdd(&counts[ei[E + e]], 1);
    return;
  }
  // GEMM part: A=W (512 ch), B=x^T; 32 rows/wave
  int wave = threadIdx.x >> 6, lane = threadIdx.x & 63;
  int lr = lane & 15, kb = (lane >> 4) * 8;
  int rowbase = blockIdx.x*128 + wave*32;

  union FR { bf16x8 v; unsigned u[4]; uint4 u4; };
  FR bfr[2][4];
  int myrow[2]; bool wr[2];
  #pragma unroll
  for (int rg = 0; rg < 2; ++rg){
    myrow[rg] = rowbase + rg*16 + lr;
    int rc = myrow[rg] < n ? myrow[rg] : n-1;
    wr[rg] = myrow[rg] < n;
    const float* xp = &x[(size_t)rc*128];
    #pragma unroll
    for (int ks = 0; ks < 4; ++ks){
      float4 f0 = *reinterpret_cast<const float4*>(xp + ks*32 + kb);
      float4 f1 = *reinterpret_cast<const float4*>(xp + ks*32 + kb + 4);
      bfr[rg][ks].u[0] = cvtpk_bf16(f0.x, f0.y);
      bfr[rg][ks].u[1] = cvtpk_bf16(f0.z, f0.w);
      bfr[rg][ks].u[2] = cvtpk_bf16(f1.x, f1.y);
      bfr[rg][ks].u[3] = cvtpk_bf16(f1.z, f1.w);
    }
  }

  #pragma unroll 1
  for (int mt = 0; mt < 32; ++mt){
    FR afr[4];
    const unsigned short* wp = &Wb[(size_t)(mt*16 + lr)*128 + kb];
    #pragma unroll
    for (int ks = 0; ks < 4; ++ks)
      afr[ks].u4 = *reinterpret_cast<const uint4*>(wp + ks*32);
    f32x4 acc0 = (f32x4){0.f,0.f,0.f,0.f};
    f32x4 acc1 = (f32x4){0.f,0.f,0.f,0.f};
    #pragma unroll
    for (int ks = 0; ks < 4; ++ks){
      acc0 = __builtin_amdgcn_mfma_f32_16x16x32_bf16(afr[ks].v, bfr[0][ks].v, acc0, 0,0,0);
      acc1 = __builtin_amdgcn_mfma_f32_16x16x32_bf16(afr[ks].v, bfr[1][ks].v, acc1, 0,0,0);
    }
    int ch0 = mt*16 + (lane>>4)*4;
    float4 bi = *reinterpret_cast<const float4*>(&bcat[ch0]);
    unsigned short* dst = (ch0 < 256) ? xl : xr;
    int cc = ch0 & 255;
    if (wr[0]){
      uint2 o; o.x = cvtpk_bf16(acc0[0]+bi.x, acc0[1]+bi.y);
      o.y = cvtpk_bf16(acc0[2]+bi.z, acc0[3]+bi.w);
      *reinterpret_cast<uint2*>(&dst[(size_t)myrow[0]*256 + cc]) = o;
    }
    if (wr[1]){
      uint2 o; o.x = cvtpk_bf16(acc1[0]+bi.x, acc1[1]+bi.y);
      o.y = cvtpk_bf16(acc1[2]+bi.z, acc1[3]+bi.w);
      *reinterpret_cast<uint2*>(&dst[(size_t)myrow[1]*256 + cc]) = o;
    }
  }
}

// ---------- 3. segment offset allocation ----------
__global__ void alloc_offsets(const int* __restrict__ counts, int n, int* __restrict__ offs,
                              int* __restrict__ total){
  int i = blockIdx.x*blockDim.x + threadIdx.x;
  int lane = threadIdx.x & 63;
  int v = (i < n) ? counts[i] : 0;
  int incl = v;
  #pragma unroll
  for (int d = 1; d < 64; d <<= 1){
    int y = __shfl_up(incl, d);
    if (lane >= d) incl += y;
  }
  int wsum = __shfl(incl, 63);
  int base = 0;
  if (lane == 0) base = atomicAdd(total, wsum);
  base = __shfl(base, 0);
  if (i < n) offs[i] = base + incl - v;
}

// ---------- 4. scatter (atomic-free) ----------
__global__ void scatter_edges(const int* __restrict__ ei, int E,
                              const int* __restrict__ offs, const int* __restrict__ rank,
                              int* __restrict__ ssrc){
  for (int e = blockIdx.x*blockDim.x + threadIdx.x; e < E; e += gridDim.x*blockDim.x){
    int d = ei[E + e];
    ssrc[offs[d] + rank[e]] = ei[e];
  }
}

// ---------- 5. node attention: uint4 gathers, depth-1 pipeline (r4-proven) ----------
__device__ inline float dot8(const float4& a0, const float4& a1,
                             const float4& xr0, const float4& xr1,
                             const float4& at0, const float4& at1){
  float t, d;
  t = a0.x+xr0.x; t = fmaxf(t, 0.2f*t); d  = at0.x*t;
  t = a0.y+xr0.y; t = fmaxf(t, 0.2f*t); d += at0.y*t;
  t = a0.z+xr0.z; t = fmaxf(t, 0.2f*t); d += at0.z*t;
  t = a0.w+xr0.w; t = fmaxf(t, 0.2f*t); d += at0.w*t;
  t = a1.x+xr1.x; t = fmaxf(t, 0.2f*t); d += at1.x*t;
  t = a1.y+xr1.y; t = fmaxf(t, 0.2f*t); d += at1.y*t;
  t = a1.z+xr1.z; t = fmaxf(t, 0.2f*t); d += at1.z*t;
  t = a1.w+xr1.w; t = fmaxf(t, 0.2f*t); d += at1.w*t;
  return d;
}
__device__ inline float red16(float d){
  d += __shfl_xor(d, 1); d += __shfl_xor(d, 2);
  d += __shfl_xor(d, 4); d += __shfl_xor(d, 8);
  return d;
}

__launch_bounds__(128)
__global__ void node_attn(const unsigned short* __restrict__ xl,
                          const unsigned short* __restrict__ xr,
                          const float* __restrict__ att, const float* __restrict__ bias,
                          const int* __restrict__ offs, const int* __restrict__ counts,
                          const int* __restrict__ ssrc,
                          float* __restrict__ out, int n){
  int lane = threadIdx.x & 63;
  int v = blockIdx.x*2 + (threadIdx.x >> 6);
  if (v >= n) return;
  int half = lane >> 5, q5 = lane & 31, h = q5 >> 4, cq = q5 & 15;
  int fbase = h*128 + cq*8;

  float4 xr0, xr1;
  up8(*reinterpret_cast<const uint4*>(&xr[(size_t)v*256 + fbase]), xr0, xr1);
  float4 at0 = *reinterpret_cast<const float4*>(&att[fbase]);
  float4 at1 = *reinterpret_cast<const float4*>(&att[fbase + 4]);

  float4 sv0, sv1;
  up8(*reinterpret_cast<const uint4*>(&xl[(size_t)v*256 + fbase]), sv0, sv1);
  float dself = red16(dot8(sv0, sv1, xr0, xr1, at0, at1));
  float m, s; float4 ac0, ac1;
  if (half == 0){ m = dself; s = 1.f; ac0 = sv0; ac1 = sv1; }
  else { m = -1e30f; s = 0.f; ac0 = make_float4(0,0,0,0); ac1 = ac0; }

  int e0 = offs[v], cnt = counts[v];
  int halfoff = half*4;
  int e = 0;
  while (e < cnt){
    int take = cnt - e; if (take > 64) take = 64;
    int last = e0 + cnt - 1;
    int idx = e0 + e + lane; if (idx > last) idx = last;
    int batch = ssrc[idx];

    uint4 c0, c1, c2, c3;
    {
      int b = halfoff;
      int i0 = __shfl(batch, b),   i1 = __shfl(batch, b+1);
      int i2 = __shfl(batch, b+2), i3 = __shfl(batch, b+3);
      c0 = *reinterpret_cast<const uint4*>(&xl[(size_t)i0*256 + fbase]);
      c1 = *reinterpret_cast<const uint4*>(&xl[(size_t)i1*256 + fbase]);
      c2 = *reinterpret_cast<const uint4*>(&xl[(size_t)i2*256 + fbase]);
      c3 = *reinterpret_cast<const uint4*>(&xl[(size_t)i3*256 + fbase]);
    }
    for (int j = 0; j < take; j += 8){
      uint4 n0, n1, n2, n3;
      bool more = (j + 8) < take;
      if (more){
        int b = j + 8 + halfoff;
        int i0 = __shfl(batch, b),   i1 = __shfl(batch, b+1);
        int i2 = __shfl(batch, b+2), i3 = __shfl(batch, b+3);
        n0 = *reinterpret_cast<const uint4*>(&xl[(size_t)i0*256 + fbase]);
        n1 = *reinterpret_cast<const uint4*>(&xl[(size_t)i1*256 + fbase]);
        n2 = *reinterpret_cast<const uint4*>(&xl[(size_t)i2*256 + fbase]);
        n3 = *reinterpret_cast<const uint4*>(&xl[(size_t)i3*256 + fbase]);
      }
      float4 a00,a01,a10,a11,a20,a21,a30,a31;
      up8(c0, a00, a01); up8(c1, a10, a11);
      up8(c2, a20, a21); up8(c3, a30, a31);
      float d0 = red16(dot8(a00,a01,xr0,xr1,at0,at1));
      float d1 = red16(dot8(a10,a11,xr0,xr1,at0,at1));
      float d2 = red16(dot8(a20,a21,xr0,xr1,at0,at1));
      float d3 = red16(dot8(a30,a31,xr0,xr1,at0,at1));

      float p0e, p1e, p2e, p3e, f;
      if (j + 8 <= take){
        float nm = fmaxf(m, fmaxf(fmaxf(d0,d1), fmaxf(d2,d3)));
        f = __expf(m - nm);
        p0e = __expf(d0-nm); p1e = __expf(d1-nm);
        p2e = __expf(d2-nm); p3e = __expf(d3-nm);
        m = nm;
      } else {
        int b0 = j + halfoff;
        bool v0 = b0 < take, v1 = b0+1 < take, v2 = b0+2 < take, v3 = b0+3 < take;
        float dm0 = v0 ? d0 : -1e30f, dm1 = v1 ? d1 : -1e30f;
        float dm2 = v2 ? d2 : -1e30f, dm3 = v3 ? d3 : -1e30f;
        float nm = fmaxf(m, fmaxf(fmaxf(dm0,dm1), fmaxf(dm2,dm3)));
        f = __expf(m - nm);
        p0e = v0 ? __expf(d0-nm) : 0.f;
        p1e = v1 ? __expf(d1-nm) : 0.f;
        p2e = v2 ? __expf(d2-nm) : 0.f;
        p3e = v3 ? __expf(d3-nm) : 0.f;
        m = nm;
      }
      s = s*f + ((p0e+p1e)+(p2e+p3e));
      ac0.x = ac0.x*f + p0e*a00.x + p1e*a10.x + p2e*a20.x + p3e*a30.x;
      ac0.y = ac0.y*f + p0e*a00.y + p1e*a10.y + p2e*a20.y + p3e*a30.y;
      ac0.z = ac0.z*f + p0e*a00.z + p1e*a10.z + p2e*a20.z + p3e*a30.z;
      ac0.w = ac0.w*f + p0e*a00.w + p1e*a10.w + p2e*a20.w + p3e*a30.w;
      ac1.x = ac1.x*f + p0e*a01.x + p1e*a11.x + p2e*a21.x + p3e*a31.x;
      ac1.y = ac1.y*f + p0e*a01.y + p1e*a11.y + p2e*a21.y + p3e*a31.y;
      ac1.z = ac1.z*f + p0e*a01.z + p1e*a11.z + p2e*a21.z + p3e*a31.z;
      ac1.w = ac1.w*f + p0e*a01.w + p1e*a11.w + p2e*a21.w + p3e*a31.w;
      if (more){ c0 = n0; c1 = n1; c2 = n2; c3 = n3; }
    }
    e += take;
  }

  // merge half-wave streams (flash-combine across xor 32)
  float mo = __shfl_xor(m, 32), so = __shfl_xor(s, 32);
  float4 bo0, bo1;
  bo0.x = __shfl_xor(ac0.x, 32); bo0.y = __shfl_xor(ac0.y, 32);
  bo0.z = __shfl_xor(ac0.z, 32); bo0.w = __shfl_xor(ac0.w, 32);
  bo1.x = __shfl_xor(ac1.x, 32); bo1.y = __shfl_xor(ac1.y, 32);
  bo1.z = __shfl_xor(ac1.z, 32); bo1.w = __shfl_xor(ac1.w, 32);
  float mm = fmaxf(m, mo);
  float fa = __expf(m - mm), fb = __expf(mo - mm);
  s = s*fa + so*fb;
  ac0.x = ac0.x*fa + bo0.x*fb; ac0.y = ac0.y*fa + bo0.y*fb;
  ac0.z = ac0.z*fa + bo0.z*fb; ac0.w = ac0.w*fa + bo0.w*fb;
  ac1.x = ac1.x*fa + bo1.x*fb; ac1.y = ac1.y*fa + bo1.y*fb;
  ac1.z = ac1.z*fa + bo1.z*fb; ac1.w = ac1.w*fa + bo1.w*fb;
  float inv = 1.f/s;
  float w0x = ac0.x*inv, w0y = ac0.y*inv, w0z = ac0.z*inv, w0w = ac0.w*inv;
  float w1x = ac1.x*inv, w1y = ac1.y*inv, w1z = ac1.z*inv, w1w = ac1.w*inv;
  float o0x = __shfl_xor(w0x, 16), o0y = __shfl_xor(w0y, 16);
  float o0z = __shfl_xor(w0z, 16), o0w = __shfl_xor(w0w, 16);
  float o1x = __shfl_xor(w1x, 16), o1y = __shfl_xor(w1y, 16);
  float o1z = __shfl_xor(w1z, 16), o1w = __shfl_xor(w1w, 16);
  if (half == 0 && h == 0){
    float4 b0 = *reinterpret_cast<const float4*>(&bias[cq*8]);
    float4 b1 = *reinterpret_cast<const float4*>(&bias[cq*8 + 4]);
    float4 r0, r1;
    r0.x = 0.5f*(w0x+o0x) + b0.x; r0.y = 0.5f*(w0y+o0y) + b0.y;
    r0.z = 0.5f*(w0z+o0z) + b0.z; r0.w = 0.5f*(w0w+o0w) + b0.w;
    r1.x = 0.5f*(w1x+o1x) + b1.x; r1.y = 0.5f*(w1y+o1y) + b1.y;
    r1.z = 0.5f*(w1z+o1z) + b1.z; r1.w = 0.5f*(w1w+o1w) + b1.w;
    *reinterpret_cast<float4*>(&out[(size_t)v*128 + cq*8])     = r0;
    *reinterpret_cast<float4*>(&out[(size_t)v*128 + cq*8 + 4]) = r1;
  }
}

// ---------- 6. column sums + last-block stats ----------
__global__ void col_reduce(const float* __restrict__ out, int n,
                           float* __restrict__ colsum, float* __restrict__ colsq,
                           const float* __restrict__ ms, float* __restrict__ stats,
                           int* __restrict__ done){
  __shared__ float s1[256*4], s2[256*4];
  __shared__ int isLast;
  int t = threadIdx.x;
  int c4 = t & 31, rg = t >> 5;
  float4 sum = make_float4(0,0,0,0), sq = make_float4(0,0,0,0);
  for (int r = blockIdx.x*8 + rg; r < n; r += gridDim.x*8){
    float4 v = reinterpret_cast<const float4*>(out)[(size_t)r*32 + c4];
    sum.x += v.x; sum.y += v.y; sum.z += v.z; sum.w += v.w;
    sq.x += v.x*v.x; sq.y += v.y*v.y; sq.z += v.z*v.z; sq.w += v.w*v.w;
  }
  reinterpret_cast<float4*>(s1)[t] = sum;
  reinterpret_cast<float4*>(s2)[t] = sq;
  __syncthreads();
  if (t < 32){
    #pragma unroll
    for (int g = 1; g < 8; ++g){
      float4 a = reinterpret_cast<float4*>(s1)[t + g*32];
      float4 b = reinterpret_cast<float4*>(s2)[t + g*32];
      sum.x += a.x; sum.y += a.y; sum.z += a.z; sum.w += a.w;
      sq.x  += b.x; sq.y  += b.y; sq.z  += b.z; sq.w  += b.w;
    }
    atomicAdd(&colsum[t*4+0], sum.x); atomicAdd(&colsum[t*4+1], sum.y);
    atomicAdd(&colsum[t*4+2], sum.z); atomicAdd(&colsum[t*4+3], sum.w);
    atomicAdd(&colsq[t*4+0], sq.x);  atomicAdd(&colsq[t*4+1], sq.y);
    atomicAdd(&colsq[t*4+2], sq.z);  atomicAdd(&colsq[t*4+3], sq.w);
  }
  __syncthreads();
  if (t == 0){
    __threadfence();
    isLast = (atomicAdd(done, 1) == (int)gridDim.x - 1);
  }
  __syncthreads();
  if (isLast && t < 128){
    float invn = 1.f/(float)n;
    float mu  = colsum[t]*invn;
    float ex2 = colsq[t]*invn;
    float mm  = ms[t];
    float var = ex2 - 2.f*mm*mu*mu + mm*mm*mu*mu;
    stats[t]     = mm*mu;
    stats[128+t] = rsqrtf(var + 1e-5f);
  }
}

// ---------- 7. normalize + ELU + residual ----------
__global__ void final_ew(float* __restrict__ out, const float* __restrict__ x,
                         const float* __restrict__ stats, const float* __restrict__ gw,
                         const float* __restrict__ gb, int n){
  int total = n*32;
  for (int i = blockIdx.x*blockDim.x + threadIdx.x; i < total; i += gridDim.x*blockDim.x){
    int c4 = i & 31;
    float4 o  = reinterpret_cast<float4*>(out)[i];
    float4 xv = reinterpret_cast<const float4*>(x)[i];
    float4 sh = reinterpret_cast<const float4*>(stats)[c4];
    float4 rs = reinterpret_cast<const float4*>(stats)[32 + c4];
    float4 w4 = reinterpret_cast<const float4*>(gw)[c4];
    float4 b4 = reinterpret_cast<const float4*>(gb)[c4];
    float y0 = w4.x*((o.x - sh.x)*rs.x) + b4.x;  y0 = y0 > 0.f ? y0 : expm1f(y0);
    float y1 = w4.y*((o.y - sh.y)*rs.y) + b4.y;  y1 = y1 > 0.f ? y1 : expm1f(y1);
    float y2 = w4.z*((o.z - sh.z)*rs.z) + b4.z;  y2 = y2 > 0.f ? y2 : expm1f(y2);
    float y3 = w4.w*((o.w - sh.w)*rs.w) + b4.w;  y3 = y3 > 0.f ? y3 : expm1f(y3);
    o.x = y0 + xv.x; o.y = y1 + xv.y; o.z = y2 + xv.z; o.w = y3 + xv.w;
    reinterpret_cast<float4*>(out)[i] = o;
  }
}

// ---------- launch ----------
extern "C" void kernel_launch(void* const* d_in, const int* in_sizes, int n_in,
                              void* d_out, int out_size, void* d_ws, size_t ws_size,
                              hipStream_t stream){
  const float* x    = (const float*)d_in[0];
  const int*   ei   = (const int*)  d_in[1];
  const float* Wl   = (const float*)d_in[2];
  const float* bl   = (const float*)d_in[3];
  const float* Wr   = (const float*)d_in[4];
  const float* br   = (const float*)d_in[5];
  const float* att  = (const float*)d_in[6];
  const float* bias = (const float*)d_in[7];
  const float* gw   = (const float*)d_in[8];
  const float* gb   = (const float*)d_in[9];
  const float* gms  = (const float*)d_in[10];
  int n = in_sizes[0] / 128;
  int E = in_sizes[1] / 2;
  float* outp = (float*)d_out;

  char* w = (char*)d_ws;
  size_t off = 0;
  auto alloc = [&](size_t bytes)->char*{
    char* p = w + off; off += (bytes + 255) & ~(size_t)255; return p;
  };
  unsigned short* xl  = (unsigned short*)alloc((size_t)n*256*2);
  unsigned short* xr  = (unsigned short*)alloc((size_t)n*256*2);
  unsigned short* Wb  = (unsigned short*)alloc(512*128*2);
  float* bcat   = (float*)alloc(512*4);
  int*   counts = (int*)  alloc((size_t)n*4);
  int*   offs   = (int*)  alloc((size_t)n*4);
  int*   zeros4 = (int*)  alloc(4*4);   // total, done
  int*   rank   = (int*)  alloc((size_t)E*4);
  int*   ssrc   = (int*)  alloc((size_t)E*4);
  float* colsum = (float*)alloc(128*4);
  float* colsq  = (float*)alloc(128*4);
  float* stats  = (float*)alloc(256*4);
  if (off > ws_size) return;
  int* total = zeros4 + 0;
  int* done  = zeros4 + 1;

  int G = (n + 127) / 128;
  prep_w       <<<256, 256, 0, stream>>>(Wl, Wr, bl, br, Wb, bcat, counts, zeros4, colsum, colsq, n);
  gemm_hist    <<<G + 256, 256, 0, stream>>>(x, Wb, bcat, xl, xr, n, G, ei, E, counts, rank);
  alloc_offsets<<<(n+255)/256, 256, 0, stream>>>(counts, n, offs, total);
  scatter_edges<<<1024, 256, 0, stream>>>(ei, E, offs, rank, ssrc);
  node_attn    <<<(n+1)/2, 128, 0, stream>>>(xl, xr, att, bias, offs, counts, ssrc, outp, n);
  col_reduce   <<<512, 256, 0, stream>>>(outp, n, colsum, colsq, gms, stats, done);
  final_ew     <<<2048, 256, 0, stream>>>(outp, x, stats, gw, gb, n);
}